// Round 13
// baseline (211.975 us; speedup 1.0000x reference)
//
#include <hip/hip_runtime.h>

// Problem constants
#define NB 256
#define NDF 768
#define NQ 96
#define NS 361
#define LDT 40        // Q staging stride (bf16 elems): 80B rows
#define LDP 392       // K2 attn LDS stride (bf16 elems): 784B rows, 16B-aligned
#define WSROW 368     // ws logits row stride (bf16 elems): 184 dwords, 16B-aligned
#define WS_LOG_BYTES ((size_t)NB * NQ * WSROW * 2)

typedef short bf16x8_t __attribute__((ext_vector_type(8)));
typedef float f32x2_t __attribute__((ext_vector_type(2)));
typedef float f32x4_t __attribute__((ext_vector_type(4)));
typedef float f32x4u_t __attribute__((ext_vector_type(4), aligned(4)));
typedef unsigned int u32x4_t __attribute__((ext_vector_type(4)));

__device__ __forceinline__ unsigned pack_hi(unsigned b_, unsigned a_) {
    return __builtin_amdgcn_perm(b_, a_, 0x07060302u);
}
__device__ __forceinline__ unsigned short f2bf(float x) {   // RNE
    unsigned u = __float_as_uint(x);
    u += 0x7FFFu + ((u >> 16) & 1u);
    return (unsigned short)(u >> 16);
}
__device__ __forceinline__ float bf2f(unsigned short h) {
    return __uint_as_float(((unsigned)h) << 16);
}

// split-bf16 convert: 8 fp32 -> hi bf16x8 (trunc) + lo bf16x8 (residual, trunc)
__device__ __forceinline__ void cvt8(const float* x, bf16x8_t& hi, bf16x8_t& lo) {
    unsigned uh[8]; float fl[8];
#pragma unroll
    for (int j = 0; j < 8; ++j) {
        unsigned u = __float_as_uint(x[j]);
        uh[j] = u;
        fl[j] = x[j] - __uint_as_float(u & 0xFFFF0000u);
    }
    u32x4_t h, l;
    h[0] = pack_hi(uh[1], uh[0]); h[1] = pack_hi(uh[3], uh[2]);
    h[2] = pack_hi(uh[5], uh[4]); h[3] = pack_hi(uh[7], uh[6]);
    l[0] = pack_hi(__float_as_uint(fl[1]), __float_as_uint(fl[0]));
    l[1] = pack_hi(__float_as_uint(fl[3]), __float_as_uint(fl[2]));
    l[2] = pack_hi(__float_as_uint(fl[5]), __float_as_uint(fl[4]));
    l[3] = pack_hi(__float_as_uint(fl[7]), __float_as_uint(fl[6]));
    hi = __builtin_bit_cast(bf16x8_t, h);
    lo = __builtin_bit_cast(bf16x8_t, l);
}

// LDS-only barrier: orders LDS ops; does NOT drain vmcnt (asm loads stay in flight).
__device__ __forceinline__ void block_sync_lds() {
    asm volatile("s_waitcnt lgkmcnt(0)" ::: "memory");
    __builtin_amdgcn_s_barrier();
    __builtin_amdgcn_sched_barrier(0);
}

// Raw asm loads: volatile => issue order pinned, outputs cannot be sunk.
#define GLD(D, A)       asm volatile("global_load_dword %0, %1, off" : "=v"(D) : "v"(A))
#define GLDO(D, A, O)   asm volatile("global_load_dword %0, %1, off offset:" #O : "=v"(D) : "v"(A))
#define GLD2(D, A)      asm volatile("global_load_dwordx2 %0, %1, off" : "=v"(D) : "v"(A))
#define GLD2O(D, A, O)  asm volatile("global_load_dwordx2 %0, %1, off offset:" #O : "=v"(D) : "v"(A))
#define VMWAIT(N) { asm volatile("s_waitcnt vmcnt(" #N ")"); __builtin_amdgcn_sched_barrier(0); }

// ================= K1: GEMM1 (split-bf16) + softmax over q =================
// grid NB*2 (batch, s-half of 192), 384 thr = 6 waves; wave: 2 interleaved s-tiles
// (cols 2*ll, 2*ll+1) x 6 q-tiles. ctx loads = dwordx2 pairs (8B/lane, 128B runs).
// 2-chunk-ahead asm FIFO: per chunk 16 VMEM issued (Q(c+2):8 + ctx(c+2):8);
// vmcnt(32) completes ctx(c) for MFMA, vmcnt(24) completes Q(c+1) for staging.
// Queue never empties (24-40 instrs in flight per wave at all times).
template<int MODE>
__global__ __launch_bounds__(384, 3) void k1_gemm1_softmaxq(
    const float* __restrict__ Qg, const float* __restrict__ Cg,
    unsigned short* __restrict__ WsLog, float* __restrict__ AoutF)
{
    __shared__ __align__(16) unsigned short sQhi[2][NQ * LDT];
    __shared__ __align__(16) unsigned short sQlo[2][NQ * LDT];

    // XCD-pairing swizzle (grid 512 = 8 xcd * 32 batch-groups * 2 halves)
    const int x = blockIdx.x;
    const int b = (x & 7) * 32 + (x >> 4);
    const int h = (x >> 3) & 1;

    const int tid = threadIdx.x;
    const int wv = tid >> 6;
    const int lane = tid & 63;
    const int ll = lane & 15;
    const int lg = lane >> 4;
    const int llh = (ll >> 3) & 1;
    const int s0 = 192 * h;
    const int qq = tid % 96;
    const int koct = tid / 96;         // 0..3
    // paired s-columns: raw start; clamp keeps dwordx2 in-bounds; bsel fixes the
    // one boundary lane (raw==360) whose real col-360 lands in slot 1.
    const int spRaw = s0 + 32 * wv + 2 * ll;
    const int sp0c  = min(spRaw, NS - 2);
    const bool bsel = (spRaw > NS - 2);
    // swizzled Q-tile store offset (shorts): row=qq, col8 = koct ^ ((qq>>3)&3)
    const int stoff = qq * LDT + 8 * (koct ^ ((qq >> 3) & 3));

    const float* __restrict__ qg = Qg + (size_t)b * NDF * NQ;   // [768][96]
    const float* __restrict__ cg = Cg + (size_t)b * NDF * NS;   // [768][361]
    const float* __restrict__ cgl = cg + sp0c;                  // per-lane ctx base

    f32x4_t acc[6][2];
#pragma unroll
    for (int i = 0; i < 6; ++i)
#pragma unroll
        for (int j = 0; j < 2; ++j) acc[i][j] = (f32x4_t)0.0f;

    float qv0[8], qv1[8];
    f32x2_t rcA[8], rcB[8], rcC[8];

// 8 Q loads: rows K0+8*koct..+7, col qq. Stride NQ*4 = 384 B.
#define ISSUE_Q(K0, QV) { \
    unsigned long long qa = (unsigned long long)(qg + ((K0) + 8 * koct) * NQ + qq); \
    GLD (QV[0], qa);        GLDO(QV[1], qa, 384); \
    GLDO(QV[2], qa, 768);   GLDO(QV[3], qa, 1152); \
    GLDO(QV[4], qa, 1536);  GLDO(QV[5], qa, 1920); \
    GLDO(QV[6], qa, 2304);  GLDO(QV[7], qa, 2688); }

// 8 ctx dwordx2 loads: rows K0+8*lg..+7, col pair (sp0c, sp0c+1). Stride 1444 B.
#define ISSUE_CTX(K0, R) { \
    unsigned long long p0 = (unsigned long long)(cgl + (size_t)((K0) + 8 * lg) * NS); \
    unsigned long long p1 = p0 + 3u * 1444u; \
    unsigned long long p2 = p0 + 6u * 1444u; \
    GLD2 (R[0], p0); GLD2O(R[1], p0, 1444); GLD2O(R[2], p0, 2888); \
    GLD2 (R[3], p1); GLD2O(R[4], p1, 1444); GLD2O(R[5], p1, 2888); \
    GLD2 (R[6], p2); GLD2O(R[7], p2, 1444); }

#define STAGEQ(QV, CUR) { \
    bf16x8_t qh, ql; \
    cvt8(QV, qh, ql); \
    *(bf16x8_t*)&sQhi[CUR][stoff] = qh; \
    *(bf16x8_t*)&sQlo[CUR][stoff] = ql; }

#define MFMAPH(R, CUR) { \
    float xe[8], xo[8]; \
    _Pragma("unroll") \
    for (int j = 0; j < 8; ++j) { \
        xe[j] = bsel ? R[j][1] : R[j][0]; \
        xo[j] = R[j][1]; } \
    bf16x8_t B0h, B0l, B1h, B1l; \
    cvt8(xe, B0h, B0l); \
    cvt8(xo, B1h, B1l); \
    _Pragma("unroll") \
    for (int mt = 0; mt < 6; ++mt) { \
        int ro = (16 * mt + ll) * LDT + 8 * (lg ^ ((2 * mt + llh) & 3)); \
        bf16x8_t Ah = *(const bf16x8_t*)&sQhi[CUR][ro]; \
        bf16x8_t Al = *(const bf16x8_t*)&sQlo[CUR][ro]; \
        acc[mt][0] = __builtin_amdgcn_mfma_f32_16x16x32_bf16(Ah, B0h, acc[mt][0], 0, 0, 0); \
        acc[mt][0] = __builtin_amdgcn_mfma_f32_16x16x32_bf16(Ah, B0l, acc[mt][0], 0, 0, 0); \
        acc[mt][0] = __builtin_amdgcn_mfma_f32_16x16x32_bf16(Al, B0h, acc[mt][0], 0, 0, 0); \
        acc[mt][1] = __builtin_amdgcn_mfma_f32_16x16x32_bf16(Ah, B1h, acc[mt][1], 0, 0, 0); \
        acc[mt][1] = __builtin_amdgcn_mfma_f32_16x16x32_bf16(Ah, B1l, acc[mt][1], 0, 0, 0); \
        acc[mt][1] = __builtin_amdgcn_mfma_f32_16x16x32_bf16(Al, B1h, acc[mt][1], 0, 0, 0); } }

// Steady-state iteration for chunk C: at entry in-flight = [ctx(C):8][Q(C+1):8][ctx(C+1):8].
#define ITER(C, USE, FILL, QISS, QSTG, CUR, NXT) { \
    ISSUE_Q(((C) + 2) * 32, QISS); \
    ISSUE_CTX(((C) + 2) * 32, FILL); \
    VMWAIT(32); \
    MFMAPH(USE, CUR); \
    VMWAIT(24); \
    STAGEQ(QSTG, NXT); \
    block_sync_lds(); }

    // prologue
    ISSUE_Q(0, qv0);   ISSUE_CTX(0, rcA);    // 16 in flight
    ISSUE_Q(32, qv1);  ISSUE_CTX(32, rcB);   // 32 in flight
    VMWAIT(24);                              // Q(0) done
    STAGEQ(qv0, 0);
    block_sync_lds();

    for (int cc = 0; cc < 18; cc += 6) {
        ITER(cc + 0, rcA, rcC, qv0, qv1, 0, 1);
        ITER(cc + 1, rcB, rcA, qv1, qv0, 1, 0);
        ITER(cc + 2, rcC, rcB, qv0, qv1, 0, 1);
        ITER(cc + 3, rcA, rcC, qv1, qv0, 1, 0);
        ITER(cc + 4, rcB, rcA, qv0, qv1, 0, 1);
        ITER(cc + 5, rcC, rcB, qv1, qv0, 1, 0);
    }
    ITER(18, rcA, rcC, qv0, qv1, 0, 1);
    ITER(19, rcB, rcA, qv1, qv0, 1, 0);
    ITER(20, rcC, rcB, qv0, qv1, 0, 1);
    ITER(21, rcA, rcC, qv1, qv0, 1, 0);
    // chunk 22 (no new issue): in-flight = [ctx22:8][Q23:8][ctx23:8]
    VMWAIT(16);
    MFMAPH(rcB, 0);
    VMWAIT(8);
    STAGEQ(qv1, 1);
    block_sync_lds();
    // chunk 23
    VMWAIT(0);
    MFMAPH(rcC, 1);

#undef ISSUE_Q
#undef ISSUE_CTX
#undef STAGEQ
#undef MFMAPH
#undef ITER

    // softmax over q (per s-col), fold *4; col(s of nt) = s0+32wv+2*ll+nt
#pragma unroll
    for (int nt = 0; nt < 2; ++nt) {
        float m = -3.0e38f;
#pragma unroll
        for (int mt = 0; mt < 6; ++mt)
#pragma unroll
            for (int r = 0; r < 4; ++r) m = fmaxf(m, acc[mt][nt][r]);
        m = fmaxf(m, __shfl_xor(m, 16));
        m = fmaxf(m, __shfl_xor(m, 32));
        float sum = 0.0f;
#pragma unroll
        for (int mt = 0; mt < 6; ++mt)
#pragma unroll
            for (int r = 0; r < 4; ++r) {
                float e = __expf(acc[mt][nt][r] - m);
                acc[mt][nt][r] = e;
                sum += e;
            }
        sum += __shfl_xor(sum, 16);
        sum += __shfl_xor(sum, 32);
        float inv = 4.0f / sum;     // fold TEMP1
#pragma unroll
        for (int mt = 0; mt < 6; ++mt)
#pragma unroll
            for (int r = 0; r < 4; ++r) acc[mt][nt][r] *= inv;
    }

    if constexpr (MODE >= 1) {
        unsigned short* wr = WsLog + (size_t)b * NQ * WSROW;
#pragma unroll
        for (int mt = 0; mt < 6; ++mt)
#pragma unroll
            for (int nt = 0; nt < 2; ++nt)
#pragma unroll
                for (int r = 0; r < 4; ++r) {
                    int q = 16 * mt + 4 * lg + r;
                    int s = s0 + 32 * wv + 2 * ll + nt;
                    if (s < NS) wr[q * WSROW + s] = f2bf(acc[mt][nt][r]);
                }
    } else {
        float* aout = AoutF + (size_t)b * NQ * NS;
#pragma unroll
        for (int mt = 0; mt < 6; ++mt)
#pragma unroll
            for (int nt = 0; nt < 2; ++nt)
#pragma unroll
                for (int r = 0; r < 4; ++r) {
                    int q = 16 * mt + 4 * lg + r;
                    int s = s0 + 32 * wv + 2 * ll + nt;
                    if (s < NS) aout[(size_t)q * NS + s] = acc[mt][nt][r];
                }
    }
}

// ================= K15 (fallback only): in-place softmax over s =================
__global__ __launch_bounds__(256) void k15_softmaxs(float* __restrict__ Aout)
{
    const int b = blockIdx.x;
    const int q = blockIdx.y * 4 + (threadIdx.x >> 6);
    const int lane = threadIdx.x & 63;
    float* __restrict__ row = Aout + ((size_t)b * NQ + q) * NS;
    const int c0 = 6 * lane;

    float v[6];
#pragma unroll
    for (int i = 0; i < 6; ++i) v[i] = (c0 + i < NS) ? row[c0 + i] : -INFINITY;
    float m = v[0];
#pragma unroll
    for (int i = 1; i < 6; ++i) m = fmaxf(m, v[i]);
#pragma unroll
    for (int o = 1; o < 64; o <<= 1) m = fmaxf(m, __shfl_xor(m, o));
    float e[6], sum = 0.0f;
#pragma unroll
    for (int i = 0; i < 6; ++i) { e[i] = __expf(v[i] - m); sum += e[i]; }
#pragma unroll
    for (int o = 1; o < 64; o <<= 1) sum += __shfl_xor(sum, o);
    float inv = 1.0f / sum;
#pragma unroll
    for (int i = 0; i < 6; ++i) if (c0 + i < NS) row[c0 + i] = e[i] * inv;
}

// ================= K2: [fused softmax-s +] GEMM2 (unchanged from r12) =================
template<bool FUSED>
__global__ __launch_bounds__(512, 4) void k2_gemm2(
    const float* __restrict__ Cg, const unsigned short* __restrict__ WsLog,
    const float* __restrict__ AttnF, float* __restrict__ Wout, float* __restrict__ AoutF)
{
    extern __shared__ char smem2[];
    unsigned short* sP = (unsigned short*)smem2;      // [96][LDP]
    unsigned* sPd = (unsigned*)smem2;                 // dword view, stride 196
    float* sMax = (float*)(smem2 + NQ * LDP * 2);     // [96]
    float* sInv = sMax + NQ;                          // [96]

    const int x = blockIdx.x;
    const int b = (x & 7) * 32 + (x >> 5);
    const int quarter = (x >> 3) & 3;
    const int tid = threadIdx.x;
    const int wv = tid >> 6;
    const int lane = tid & 63;
    const int ll = lane & 15;
    const int lg = lane >> 4;

    if constexpr (FUSED) {
        const unsigned* __restrict__ wsd = (const unsigned*)(WsLog + (size_t)b * NQ * WSROW);
        for (int i = tid; i < NQ * 184; i += 512) {
            int r = i / 184, c = i - r * 184;
            sPd[r * 196 + c] = wsd[i];
        }
        for (int i = tid; i < NQ * 12; i += 512) {
            int r = i / 12, c = i - r * 12;
            sPd[r * 196 + 184 + c] = 0;
        }
        __syncthreads();

        const int l32 = tid & 31;
        const int rbase = tid >> 5;
#pragma unroll
        for (int pass = 0; pass < 6; ++pass) {
            int row = pass * 16 + rbase;
            float m = -3.0e38f;
#pragma unroll
            for (int j = 0; j < 6; ++j) {
                int dw = l32 + 32 * j;
                if (dw < 184) {
                    unsigned u = sPd[row * 196 + dw];
                    float v0 = bf2f((unsigned short)(u & 0xFFFFu));
                    float v1 = bf2f((unsigned short)(u >> 16));
                    if (2 * dw < NS) m = fmaxf(m, v0);
                    if (2 * dw + 1 < NS) m = fmaxf(m, v1);
                }
            }
#pragma unroll
            for (int o = 1; o < 32; o <<= 1) m = fmaxf(m, __shfl_xor(m, o));
            if (l32 == 0) sMax[row] = m;
        }
        __syncthreads();
#pragma unroll
        for (int pass = 0; pass < 6; ++pass) {
            int row = pass * 16 + rbase;
            float m = sMax[row];
            float sum = 0.0f;
#pragma unroll
            for (int j = 0; j < 6; ++j) {
                int dw = l32 + 32 * j;
                if (dw < 184) {
                    unsigned u = sPd[row * 196 + dw];
                    float v0 = bf2f((unsigned short)(u & 0xFFFFu));
                    float v1 = bf2f((unsigned short)(u >> 16));
                    float e0 = (2 * dw < NS) ? __expf(v0 - m) : 0.0f;
                    float e1 = (2 * dw + 1 < NS) ? __expf(v1 - m) : 0.0f;
                    sum += e0 + e1;
                    sPd[row * 196 + dw] = ((unsigned)f2bf(e1) << 16) | (unsigned)f2bf(e0);
                }
            }
#pragma unroll
            for (int o = 1; o < 32; o <<= 1) sum += __shfl_xor(sum, o);
            if (l32 == 0) sInv[row] = sum;
        }
        __syncthreads();
        if (tid < NQ) sInv[tid] = 1.0f / sInv[tid];
        __syncthreads();
        if (quarter == 0) {
            float* aout = AoutF + (size_t)b * NQ * NS;
            for (int i = tid; i < NQ * NS; i += 512) {
                int q = i / NS, s = i - q * NS;
                aout[i] = bf2f(sP[q * LDP + s]) * sInv[q];
            }
        }
    } else {
        const float* __restrict__ attn = AttnF + (size_t)b * NQ * NS;
        for (int i = tid; i < NQ * 181; i += 512) {
            int row = i / 181, p = i - row * 181;
            float x0 = attn[row * NS + 2 * p];
            float x1 = (p < 180) ? attn[row * NS + 2 * p + 1] : 0.0f;
            sPd[row * 196 + p] = pack_hi(__float_as_uint(x1), __float_as_uint(x0));
        }
        for (int i = tid; i < NQ * 15; i += 512) {
            int row = i / 15, p = i - row * 15;
            sPd[row * 196 + 181 + p] = 0;
        }
        __syncthreads();
    }

    f32x4_t acc[3][3];
#pragma unroll
    for (int i = 0; i < 3; ++i)
#pragma unroll
        for (int j = 0; j < 3; ++j) acc[i][j] = (f32x4_t)0.0f;

    const int dw = wv >> 1, qw = wv & 1;
    const float* __restrict__ cq = Cg + (size_t)b * NDF * NS + (size_t)(quarter * 192) * NS;

#pragma unroll
    for (int c = 0; c < 12; ++c) {
        bf16x8_t Bf[3];
#pragma unroll
        for (int nt = 0; nt < 3; ++nt) {
            int row = 16 * (3 * qw + nt) + ll;
            Bf[nt] = *(const bf16x8_t*)&sP[row * LDP + 32 * c + 8 * lg];
        }
#pragma unroll
        for (int i = 0; i < 3; ++i) {
            int d = 16 * (3 * dw + i) + ll;
            const float* ap = cq + (size_t)d * NS + 32 * c + 8 * lg;
            u32x4_t u;
            if (c < 11) {
                f32x4u_t a0 = *(const f32x4u_t*)ap;
                f32x4u_t a1 = *(const f32x4u_t*)(ap + 4);
                u[0] = pack_hi(__float_as_uint(a0[1]), __float_as_uint(a0[0]));
                u[1] = pack_hi(__float_as_uint(a0[3]), __float_as_uint(a0[2]));
                u[2] = pack_hi(__float_as_uint(a1[1]), __float_as_uint(a1[0]));
                u[3] = pack_hi(__float_as_uint(a1[3]), __float_as_uint(a1[2]));
            } else {
                float t[8];
#pragma unroll
                for (int e = 0; e < 8; ++e) {
                    int s = 352 + 8 * lg + e;
                    t[e] = (s < NS) ? ap[e] : 0.0f;
                }
                u[0] = pack_hi(__float_as_uint(t[1]), __float_as_uint(t[0]));
                u[1] = pack_hi(__float_as_uint(t[3]), __float_as_uint(t[2]));
                u[2] = pack_hi(__float_as_uint(t[5]), __float_as_uint(t[4]));
                u[3] = pack_hi(__float_as_uint(t[7]), __float_as_uint(t[6]));
            }
            bf16x8_t Af = __builtin_bit_cast(bf16x8_t, u);
#pragma unroll
            for (int nt = 0; nt < 3; ++nt)
                acc[i][nt] = __builtin_amdgcn_mfma_f32_16x16x32_bf16(Af, Bf[nt], acc[i][nt], 0, 0, 0);
        }
    }

    float* wout = Wout + (size_t)b * NDF * NQ;
    float invq[3];
#pragma unroll
    for (int nt = 0; nt < 3; ++nt) {
        if constexpr (FUSED) invq[nt] = sInv[16 * (3 * qw + nt) + ll];
        else invq[nt] = 1.0f;
    }
#pragma unroll
    for (int i = 0; i < 3; ++i)
#pragma unroll
        for (int nt = 0; nt < 3; ++nt)
#pragma unroll
            for (int r = 0; r < 4; ++r) {
                int d = quarter * 192 + 16 * (3 * dw + i) + 4 * lg + r;
                int q = 16 * (3 * qw + nt) + ll;
                wout[(size_t)d * NQ + q] = acc[i][nt][r] * invq[nt];
            }
}

extern "C" void kernel_launch(void* const* d_in, const int* in_sizes, int n_in,
                              void* d_out, int out_size, void* d_ws, size_t ws_size,
                              hipStream_t stream) {
    const float* Qg = (const float*)d_in[0];
    const float* Cg = (const float*)d_in[1];
    float* Wout = (float*)d_out;
    float* Aout = Wout + (size_t)NB * NDF * NQ;   // outputs: weighted_context, attn_map

    const int smem2 = NQ * LDP * 2 + NQ * 8;      // 76032 B

    if (ws_size >= WS_LOG_BYTES) {
        unsigned short* wsLog = (unsigned short*)d_ws;
        k1_gemm1_softmaxq<1><<<dim3(NB * 2), dim3(384), 0, stream>>>(Qg, Cg, wsLog, nullptr);
        (void)hipFuncSetAttribute((const void*)k2_gemm2<true>,
                                  hipFuncAttributeMaxDynamicSharedMemorySize, smem2);
        k2_gemm2<true><<<dim3(NB * 4), dim3(512), smem2, stream>>>(
            Cg, wsLog, nullptr, Wout, Aout);
    } else {
        k1_gemm1_softmaxq<0><<<dim3(NB * 2), dim3(384), 0, stream>>>(Qg, Cg, nullptr, Aout);
        k15_softmaxs<<<dim3(NB, 24), dim3(256), 0, stream>>>(Aout);
        (void)hipFuncSetAttribute((const void*)k2_gemm2<false>,
                                  hipFuncAttributeMaxDynamicSharedMemorySize, smem2);
        k2_gemm2<false><<<dim3(NB * 4), dim3(512), smem2, stream>>>(
            Cg, nullptr, Aout, Wout, Aout);
    }
}

// Round 15
// 211.858 us; speedup vs baseline: 1.0006x; 1.0006x over previous
//
#include <hip/hip_runtime.h>

// Problem constants
#define NB 256
#define NDF 768
#define NQ 96
#define NS 361
#define LDT 40        // Q staging stride (bf16 elems): 80B rows
#define LDP 392       // K2 attn LDS stride (bf16 elems): 784B rows, 16B-aligned
#define WSROW 368     // ws logits row stride (bf16 elems): 184 dwords
#define CSROW 368     // ws ctx row stride (bf16 elems): 184 dwords
#define WS_LOG_BYTES ((size_t)NB * NQ * WSROW * 2)
#define WS_CTX_BYTES ((size_t)NB * NDF * CSROW * 2)
#define WS_FULL_BYTES (WS_LOG_BYTES + WS_CTX_BYTES)

typedef short bf16x8_t __attribute__((ext_vector_type(8)));
typedef float f32x2_t __attribute__((ext_vector_type(2)));
typedef float f32x4_t __attribute__((ext_vector_type(4)));
typedef float f32x4u_t __attribute__((ext_vector_type(4), aligned(4)));
typedef unsigned int u32x4_t __attribute__((ext_vector_type(4)));

__device__ __forceinline__ unsigned pack_hi(unsigned b_, unsigned a_) {
    return __builtin_amdgcn_perm(b_, a_, 0x07060302u);
}
__device__ __forceinline__ unsigned short f2bf(float x) {   // RNE
    unsigned u = __float_as_uint(x);
    u += 0x7FFFu + ((u >> 16) & 1u);
    return (unsigned short)(u >> 16);
}
__device__ __forceinline__ float bf2f(unsigned short h) {
    return __uint_as_float(((unsigned)h) << 16);
}

// split-bf16 convert: 8 fp32 -> hi bf16x8 (trunc) + lo bf16x8 (residual, trunc)
__device__ __forceinline__ void cvt8(const float* x, bf16x8_t& hi, bf16x8_t& lo) {
    unsigned uh[8]; float fl[8];
#pragma unroll
    for (int j = 0; j < 8; ++j) {
        unsigned u = __float_as_uint(x[j]);
        uh[j] = u;
        fl[j] = x[j] - __uint_as_float(u & 0xFFFF0000u);
    }
    u32x4_t h, l;
    h[0] = pack_hi(uh[1], uh[0]); h[1] = pack_hi(uh[3], uh[2]);
    h[2] = pack_hi(uh[5], uh[4]); h[3] = pack_hi(uh[7], uh[6]);
    l[0] = pack_hi(__float_as_uint(fl[1]), __float_as_uint(fl[0]));
    l[1] = pack_hi(__float_as_uint(fl[3]), __float_as_uint(fl[2]));
    l[2] = pack_hi(__float_as_uint(fl[5]), __float_as_uint(fl[4]));
    l[3] = pack_hi(__float_as_uint(fl[7]), __float_as_uint(fl[6]));
    hi = __builtin_bit_cast(bf16x8_t, h);
    lo = __builtin_bit_cast(bf16x8_t, l);
}

// LDS-only barrier: orders LDS ops; does NOT drain vmcnt (asm VMEM stays in flight).
__device__ __forceinline__ void block_sync_lds() {
    asm volatile("s_waitcnt lgkmcnt(0)" ::: "memory");
    __builtin_amdgcn_s_barrier();
    __builtin_amdgcn_sched_barrier(0);
}

// Raw asm VMEM: volatile => issue order pinned, outputs cannot be sunk.
#define GLD(D, A)       asm volatile("global_load_dword %0, %1, off" : "=v"(D) : "v"(A))
#define GLDO(D, A, O)   asm volatile("global_load_dword %0, %1, off offset:" #O : "=v"(D) : "v"(A))
#define GLD2(D, A)      asm volatile("global_load_dwordx2 %0, %1, off" : "=v"(D) : "v"(A))
#define GLD2O(D, A, O)  asm volatile("global_load_dwordx2 %0, %1, off offset:" #O : "=v"(D) : "v"(A))
#define GST(A, D)       asm volatile("global_store_dword %0, %1, off" :: "v"(A), "v"(D))
#define GSTO(A, D, O)   asm volatile("global_store_dword %0, %1, off offset:" #O :: "v"(A), "v"(D))
#define VMWAIT_(N) { asm volatile("s_waitcnt vmcnt(" #N ")"); __builtin_amdgcn_sched_barrier(0); }
#define VMWAIT(N) VMWAIT_(N)

// ================= K1: GEMM1 (split-bf16) + softmax over q =================
// grid NB*2 (batch, s-half of 192), 384 thr = 6 waves; wave: 2 interleaved s-tiles
// (cols 2ll, 2ll+1) x 6 q-tiles. ctx loads = dwordx2 (8/chunk); 1-chunk-ahead asm
// FIFO with a SINGLE qv buffer (r14 bug: two-buffer rotation staged garbage).
// MODE 2 relays ctx-hi bf16 dword pairs into ws (8 coalesced stores/chunk,
// never drained in-loop). vmcnt (stores COUNT): MODE1 (16,8)+tail0;
// MODE2 ITER0 (16,16), steady (24,16), tail 8.
template<int MODE>
__global__ __launch_bounds__(384, 3) void k1_gemm1_softmaxq(
    const float* __restrict__ Qg, const float* __restrict__ Cg,
    unsigned short* __restrict__ WsLog, unsigned* __restrict__ WsCtxD,
    float* __restrict__ AoutF)
{
    __shared__ __align__(16) unsigned short sQhi[2][NQ * LDT];
    __shared__ __align__(16) unsigned short sQlo[2][NQ * LDT];

    // XCD-pairing swizzle (grid 512 = 8 xcd * 32 batch-groups * 2 halves)
    const int x = blockIdx.x;
    const int b = (x & 7) * 32 + (x >> 4);
    const int h = (x >> 3) & 1;

    const int tid = threadIdx.x;
    const int wv = tid >> 6;
    const int lane = tid & 63;
    const int ll = lane & 15;
    const int lg = lane >> 4;
    const int llh = (ll >> 3) & 1;
    const int s0 = 192 * h;
    const int qq = tid % 96;
    const int koct = tid / 96;         // 0..3
    const int spRaw = s0 + 32 * wv + 2 * ll;
    const int sp0c  = min(spRaw, NS - 2);
    const bool bsel = (spRaw > NS - 2);
    const int pairIdx = 96 * h + 16 * wv + ll;       // ws-ctx dword column
    const bool wok = (MODE == 2) && (pairIdx <= 180);
    const int stoff = qq * LDT + 8 * (koct ^ ((qq >> 3) & 3));

    const float* __restrict__ qg = Qg + (size_t)b * NDF * NQ;   // [768][96]
    const float* __restrict__ cg = Cg + (size_t)b * NDF * NS;   // [768][361]
    const float* __restrict__ cgl = cg + sp0c;
    unsigned* __restrict__ wsc = (MODE == 2) ? (WsCtxD + (size_t)b * NDF * 184 + pairIdx) : nullptr;

    f32x4_t acc[6][2];
#pragma unroll
    for (int i = 0; i < 6; ++i)
#pragma unroll
        for (int j = 0; j < 2; ++j) acc[i][j] = (f32x4_t)0.0f;

    float qv[8];
    f32x2_t rcA[8], rcB[8];

#define ISSUE_Q(K0) { \
    unsigned long long qa = (unsigned long long)(qg + ((K0) + 8 * koct) * NQ + qq); \
    GLD (qv[0], qa);        GLDO(qv[1], qa, 384); \
    GLDO(qv[2], qa, 768);   GLDO(qv[3], qa, 1152); \
    GLDO(qv[4], qa, 1536);  GLDO(qv[5], qa, 1920); \
    GLDO(qv[6], qa, 2304);  GLDO(qv[7], qa, 2688); }

#define ISSUE_CTX(K0, R) { \
    unsigned long long p0 = (unsigned long long)(cgl + (size_t)((K0) + 8 * lg) * NS); \
    unsigned long long p1 = p0 + 3u * 1444u; \
    unsigned long long p2 = p0 + 6u * 1444u; \
    GLD2 (R[0], p0); GLD2O(R[1], p0, 1444); GLD2O(R[2], p0, 2888); \
    GLD2 (R[3], p1); GLD2O(R[4], p1, 1444); GLD2O(R[5], p1, 2888); \
    GLD2 (R[6], p2); GLD2O(R[7], p2, 1444); }

// relay ctx-hi bf16 pairs; rows K0+8lg..+7 at dword col pairIdx (184 dw = 736 B rows)
#define ISSUE_ST(K0, R) { \
    if (wok) { \
        unsigned st[8]; \
        _Pragma("unroll") \
        for (int j = 0; j < 8; ++j) { \
            unsigned lo_ = bsel ? __float_as_uint(R[j][1]) : __float_as_uint(R[j][0]); \
            unsigned hi_ = bsel ? 0u : __float_as_uint(R[j][1]); \
            st[j] = pack_hi(hi_, lo_); \
        } \
        unsigned long long a0 = (unsigned long long)(wsc + (size_t)((K0) + 8 * lg) * 184); \
        unsigned long long a1 = a0 + 4416u; \
        GST (a0, st[0]); GSTO(a0, st[1], 736); GSTO(a0, st[2], 1472); \
        GSTO(a0, st[3], 2208); GSTO(a0, st[4], 2944); GSTO(a0, st[5], 3680); \
        GST (a1, st[6]); GSTO(a1, st[7], 736); } }

#define STAGEQ(CUR) { \
    bf16x8_t qh, ql; \
    cvt8(qv, qh, ql); \
    *(bf16x8_t*)&sQhi[CUR][stoff] = qh; \
    *(bf16x8_t*)&sQlo[CUR][stoff] = ql; }

#define MFMAPH(R, CUR) { \
    float xe[8], xo[8]; \
    _Pragma("unroll") \
    for (int j = 0; j < 8; ++j) { \
        xe[j] = bsel ? R[j][1] : R[j][0]; \
        xo[j] = R[j][1]; } \
    bf16x8_t B0h, B0l, B1h, B1l; \
    cvt8(xe, B0h, B0l); \
    cvt8(xo, B1h, B1l); \
    _Pragma("unroll") \
    for (int mt = 0; mt < 6; ++mt) { \
        int ro = (16 * mt + ll) * LDT + 8 * (lg ^ ((2 * mt + llh) & 3)); \
        bf16x8_t Ah = *(const bf16x8_t*)&sQhi[CUR][ro]; \
        bf16x8_t Al = *(const bf16x8_t*)&sQlo[CUR][ro]; \
        acc[mt][0] = __builtin_amdgcn_mfma_f32_16x16x32_bf16(Ah, B0h, acc[mt][0], 0, 0, 0); \
        acc[mt][0] = __builtin_amdgcn_mfma_f32_16x16x32_bf16(Ah, B0l, acc[mt][0], 0, 0, 0); \
        acc[mt][0] = __builtin_amdgcn_mfma_f32_16x16x32_bf16(Al, B0h, acc[mt][0], 0, 0, 0); \
        acc[mt][1] = __builtin_amdgcn_mfma_f32_16x16x32_bf16(Ah, B1h, acc[mt][1], 0, 0, 0); \
        acc[mt][1] = __builtin_amdgcn_mfma_f32_16x16x32_bf16(Ah, B1l, acc[mt][1], 0, 0, 0); \
        acc[mt][1] = __builtin_amdgcn_mfma_f32_16x16x32_bf16(Al, B1h, acc[mt][1], 0, 0, 0); } }

// ITER(c): issue Q(c+1) into qv + ctx(c+1) into FILL; W1 completes ctx(c);
// relay-store ctx(c); MFMA on ctx(c); W2 completes Q(c+1); stage qv.
#define ITER(C, USE, FILL, CUR, NXT, W1, W2) { \
    ISSUE_Q(((C) + 1) * 32); \
    ISSUE_CTX(((C) + 1) * 32, FILL); \
    VMWAIT(W1); \
    ISSUE_ST((C) * 32, USE); \
    MFMAPH(USE, CUR); \
    VMWAIT(W2); \
    STAGEQ(NXT); \
    block_sync_lds(); }

    // prologue: [Q0:8, ctx0:8]; vmcnt(8) completes Q0
    ISSUE_Q(0);
    ISSUE_CTX(0, rcA);
    VMWAIT(8);
    STAGEQ(0);
    block_sync_lds();

    if constexpr (MODE == 2) {
        ITER(0, rcA, rcB, 0, 1, 16, 16);
        for (int c = 1; c < 22; c += 2) {
            ITER(c,     rcB, rcA, 1, 0, 24, 16);
            ITER(c + 1, rcA, rcB, 0, 1, 24, 16);
        }
        // tail chunk 23: entry [ctx23:8, st22:8]
        VMWAIT(8);
        ISSUE_ST(23 * 32, rcB);
        MFMAPH(rcB, 1);
    } else {
        ITER(0, rcA, rcB, 0, 1, 16, 8);
        for (int c = 1; c < 22; c += 2) {
            ITER(c,     rcB, rcA, 1, 0, 16, 8);
            ITER(c + 1, rcA, rcB, 0, 1, 16, 8);
        }
        VMWAIT(0);
        MFMAPH(rcB, 1);
    }

#undef ISSUE_Q
#undef ISSUE_CTX
#undef ISSUE_ST
#undef STAGEQ
#undef MFMAPH
#undef ITER

    // softmax over q (per s-col), fold *4; col(s of nt) = s0+32wv+2*ll+nt
#pragma unroll
    for (int nt = 0; nt < 2; ++nt) {
        float m = -3.0e38f;
#pragma unroll
        for (int mt = 0; mt < 6; ++mt)
#pragma unroll
            for (int r = 0; r < 4; ++r) m = fmaxf(m, acc[mt][nt][r]);
        m = fmaxf(m, __shfl_xor(m, 16));
        m = fmaxf(m, __shfl_xor(m, 32));
        float sum = 0.0f;
#pragma unroll
        for (int mt = 0; mt < 6; ++mt)
#pragma unroll
            for (int r = 0; r < 4; ++r) {
                float e = __expf(acc[mt][nt][r] - m);
                acc[mt][nt][r] = e;
                sum += e;
            }
        sum += __shfl_xor(sum, 16);
        sum += __shfl_xor(sum, 32);
        float inv = 4.0f / sum;     // fold TEMP1
#pragma unroll
        for (int mt = 0; mt < 6; ++mt)
#pragma unroll
            for (int r = 0; r < 4; ++r) acc[mt][nt][r] *= inv;
    }

    if constexpr (MODE >= 1) {
        unsigned short* wr = WsLog + (size_t)b * NQ * WSROW;
#pragma unroll
        for (int mt = 0; mt < 6; ++mt)
#pragma unroll
            for (int nt = 0; nt < 2; ++nt)
#pragma unroll
                for (int r = 0; r < 4; ++r) {
                    int q = 16 * mt + 4 * lg + r;
                    int s = s0 + 32 * wv + 2 * ll + nt;
                    if (s < NS) wr[q * WSROW + s] = f2bf(acc[mt][nt][r]);
                }
    } else {
        float* aout = AoutF + (size_t)b * NQ * NS;
#pragma unroll
        for (int mt = 0; mt < 6; ++mt)
#pragma unroll
            for (int nt = 0; nt < 2; ++nt)
#pragma unroll
                for (int r = 0; r < 4; ++r) {
                    int q = 16 * mt + 4 * lg + r;
                    int s = s0 + 32 * wv + 2 * ll + nt;
                    if (s < NS) aout[(size_t)q * NS + s] = acc[mt][nt][r];
                }
    }
    // drain all asm relay stores before dispatch-end (cross-kernel ws visibility)
    asm volatile("s_waitcnt vmcnt(0)" ::: "memory");
}

// ================= K15 (fallback only): in-place softmax over s =================
__global__ __launch_bounds__(256) void k15_softmaxs(float* __restrict__ Aout)
{
    const int b = blockIdx.x;
    const int q = blockIdx.y * 4 + (threadIdx.x >> 6);
    const int lane = threadIdx.x & 63;
    float* __restrict__ row = Aout + ((size_t)b * NQ + q) * NS;
    const int c0 = 6 * lane;

    float v[6];
#pragma unroll
    for (int i = 0; i < 6; ++i) v[i] = (c0 + i < NS) ? row[c0 + i] : -INFINITY;
    float m = v[0];
#pragma unroll
    for (int i = 1; i < 6; ++i) m = fmaxf(m, v[i]);
#pragma unroll
    for (int o = 1; o < 64; o <<= 1) m = fmaxf(m, __shfl_xor(m, o));
    float e[6], sum = 0.0f;
#pragma unroll
    for (int i = 0; i < 6; ++i) { e[i] = __expf(v[i] - m); sum += e[i]; }
#pragma unroll
    for (int o = 1; o < 64; o <<= 1) sum += __shfl_xor(sum, o);
    float inv = 1.0f / sum;
#pragma unroll
    for (int i = 0; i < 6; ++i) if (c0 + i < NS) row[c0 + i] = e[i] * inv;
}

// ================= K2: [fused softmax-s +] GEMM2 =================
// grid NB*4 (batch, d-quarter of 192), 512 thr = 8 waves (dw 0..3 x qw 0..1).
// MODE 0: attn fp32 from Aout, ctx fp32.  MODE 1: logits from ws, ctx fp32.
// MODE 2: logits from ws, ctx bf16 from ws relay (half the read bytes, no perms).
template<int MODE>
__global__ __launch_bounds__(512, 4) void k2_gemm2(
    const float* __restrict__ Cg, const unsigned short* __restrict__ WsLog,
    const unsigned short* __restrict__ WsCtx,
    const float* __restrict__ AttnF, float* __restrict__ Wout, float* __restrict__ AoutF)
{
    extern __shared__ char smem2[];
    unsigned short* sP = (unsigned short*)smem2;      // [96][LDP]
    unsigned* sPd = (unsigned*)smem2;                 // dword view, stride 196
    float* sMax = (float*)(smem2 + NQ * LDP * 2);     // [96]
    float* sInv = sMax + NQ;                          // [96]

    const int x = blockIdx.x;
    const int b = (x & 7) * 32 + (x >> 5);
    const int quarter = (x >> 3) & 3;
    const int tid = threadIdx.x;
    const int wv = tid >> 6;
    const int lane = tid & 63;
    const int ll = lane & 15;
    const int lg = lane >> 4;

    if constexpr (MODE >= 1) {
        const unsigned* __restrict__ wsd = (const unsigned*)(WsLog + (size_t)b * NQ * WSROW);
        for (int i = tid; i < NQ * 184; i += 512) {
            int r = i / 184, c = i - r * 184;
            sPd[r * 196 + c] = wsd[i];
        }
        for (int i = tid; i < NQ * 12; i += 512) {
            int r = i / 12, c = i - r * 12;
            sPd[r * 196 + 184 + c] = 0;
        }
        __syncthreads();

        const int l32 = tid & 31;
        const int rbase = tid >> 5;
#pragma unroll
        for (int pass = 0; pass < 6; ++pass) {
            int row = pass * 16 + rbase;
            float m = -3.0e38f;
#pragma unroll
            for (int j = 0; j < 6; ++j) {
                int dw = l32 + 32 * j;
                if (dw < 184) {
                    unsigned u = sPd[row * 196 + dw];
                    float v0 = bf2f((unsigned short)(u & 0xFFFFu));
                    float v1 = bf2f((unsigned short)(u >> 16));
                    if (2 * dw < NS) m = fmaxf(m, v0);
                    if (2 * dw + 1 < NS) m = fmaxf(m, v1);
                }
            }
#pragma unroll
            for (int o = 1; o < 32; o <<= 1) m = fmaxf(m, __shfl_xor(m, o));
            if (l32 == 0) sMax[row] = m;
        }
        __syncthreads();
#pragma unroll
        for (int pass = 0; pass < 6; ++pass) {
            int row = pass * 16 + rbase;
            float m = sMax[row];
            float sum = 0.0f;
#pragma unroll
            for (int j = 0; j < 6; ++j) {
                int dw = l32 + 32 * j;
                if (dw < 184) {
                    unsigned u = sPd[row * 196 + dw];
                    float v0 = bf2f((unsigned short)(u & 0xFFFFu));
                    float v1 = bf2f((unsigned short)(u >> 16));
                    float e0 = (2 * dw < NS) ? __expf(v0 - m) : 0.0f;
                    float e1 = (2 * dw + 1 < NS) ? __expf(v1 - m) : 0.0f;
                    sum += e0 + e1;
                    sPd[row * 196 + dw] = ((unsigned)f2bf(e1) << 16) | (unsigned)f2bf(e0);
                }
            }
#pragma unroll
            for (int o = 1; o < 32; o <<= 1) sum += __shfl_xor(sum, o);
            if (l32 == 0) sInv[row] = sum;
        }
        __syncthreads();
        if (tid < NQ) sInv[tid] = 1.0f / sInv[tid];
        __syncthreads();
        if (quarter == 0) {
            float* aout = AoutF + (size_t)b * NQ * NS;
            for (int i = tid; i < NQ * NS; i += 512) {
                int q = i / NS, s = i - q * NS;
                aout[i] = bf2f(sP[q * LDP + s]) * sInv[q];
            }
        }
    } else {
        const float* __restrict__ attn = AttnF + (size_t)b * NQ * NS;
        for (int i = tid; i < NQ * 181; i += 512) {
            int row = i / 181, p = i - row * 181;
            float x0 = attn[row * NS + 2 * p];
            float x1 = (p < 180) ? attn[row * NS + 2 * p + 1] : 0.0f;
            sPd[row * 196 + p] = pack_hi(__float_as_uint(x1), __float_as_uint(x0));
        }
        for (int i = tid; i < NQ * 15; i += 512) {
            int row = i / 15, p = i - row * 15;
            sPd[row * 196 + 181 + p] = 0;
        }
        __syncthreads();
    }

    // ---- GEMM2 main loop: A = ctx rows, B = sP ----
    f32x4_t acc[3][3];
#pragma unroll
    for (int i = 0; i < 3; ++i)
#pragma unroll
        for (int j = 0; j < 3; ++j) acc[i][j] = (f32x4_t)0.0f;

    const int dw = wv >> 1, qw = wv & 1;
    const float* __restrict__ cq = Cg + (size_t)b * NDF * NS + (size_t)(quarter * 192) * NS;
    const unsigned short* __restrict__ cb =
        (MODE == 2) ? (WsCtx + ((size_t)b * NDF + quarter * 192) * CSROW) : nullptr;

#pragma unroll
    for (int c = 0; c < 12; ++c) {
        bf16x8_t Bf[3];
#pragma unroll
        for (int nt = 0; nt < 3; ++nt) {
            int row = 16 * (3 * qw + nt) + ll;
            Bf[nt] = *(const bf16x8_t*)&sP[row * LDP + 32 * c + 8 * lg];
        }
#pragma unroll
        for (int i = 0; i < 3; ++i) {
            int d = 16 * (3 * dw + i) + ll;
            bf16x8_t Af;
            if constexpr (MODE == 2) {
                if (c < 11 || lg < 2) {
                    Af = *(const bf16x8_t*)&cb[(size_t)d * CSROW + 32 * c + 8 * lg];
                } else {
                    Af = (bf16x8_t)0;   // s in [368,384): beyond padded row
                }
            } else {
                const float* ap = cq + (size_t)d * NS + 32 * c + 8 * lg;
                u32x4_t u;
                if (c < 11) {
                    f32x4u_t a0 = *(const f32x4u_t*)ap;
                    f32x4u_t a1 = *(const f32x4u_t*)(ap + 4);
                    u[0] = pack_hi(__float_as_uint(a0[1]), __float_as_uint(a0[0]));
                    u[1] = pack_hi(__float_as_uint(a0[3]), __float_as_uint(a0[2]));
                    u[2] = pack_hi(__float_as_uint(a1[1]), __float_as_uint(a1[0]));
                    u[3] = pack_hi(__float_as_uint(a1[3]), __float_as_uint(a1[2]));
                } else {
                    float t[8];
#pragma unroll
                    for (int e = 0; e < 8; ++e) {
                        int s = 352 + 8 * lg + e;
                        t[e] = (s < NS) ? ap[e] : 0.0f;
                    }
                    u[0] = pack_hi(__float_as_uint(t[1]), __float_as_uint(t[0]));
                    u[1] = pack_hi(__float_as_uint(t[3]), __float_as_uint(t[2]));
                    u[2] = pack_hi(__float_as_uint(t[5]), __float_as_uint(t[4]));
                    u[3] = pack_hi(__float_as_uint(t[7]), __float_as_uint(t[6]));
                }
                Af = __builtin_bit_cast(bf16x8_t, u);
            }
#pragma unroll
            for (int nt = 0; nt < 3; ++nt)
                acc[i][nt] = __builtin_amdgcn_mfma_f32_16x16x32_bf16(Af, Bf[nt], acc[i][nt], 0, 0, 0);
        }
    }

    float* wout = Wout + (size_t)b * NDF * NQ;
    float invq[3];
#pragma unroll
    for (int nt = 0; nt < 3; ++nt) {
        if constexpr (MODE >= 1) invq[nt] = sInv[16 * (3 * qw + nt) + ll];
        else invq[nt] = 1.0f;
    }
#pragma unroll
    for (int i = 0; i < 3; ++i)
#pragma unroll
        for (int nt = 0; nt < 3; ++nt)
#pragma unroll
            for (int r = 0; r < 4; ++r) {
                int d = quarter * 192 + 16 * (3 * dw + i) + 4 * lg + r;
                int q = 16 * (3 * qw + nt) + ll;
                wout[(size_t)d * NQ + q] = acc[i][nt][r] * invq[nt];
            }
}

extern "C" void kernel_launch(void* const* d_in, const int* in_sizes, int n_in,
                              void* d_out, int out_size, void* d_ws, size_t ws_size,
                              hipStream_t stream) {
    const float* Qg = (const float*)d_in[0];
    const float* Cg = (const float*)d_in[1];
    float* Wout = (float*)d_out;
    float* Aout = Wout + (size_t)NB * NDF * NQ;   // outputs: weighted_context, attn_map

    const int smem2 = NQ * LDP * 2 + NQ * 8;      // 76032 B

    if (ws_size >= WS_FULL_BYTES) {
        unsigned short* wsLog = (unsigned short*)d_ws;
        unsigned* wsCtxD = (unsigned*)((char*)d_ws + WS_LOG_BYTES);
        k1_gemm1_softmaxq<2><<<dim3(NB * 2), dim3(384), 0, stream>>>(Qg, Cg, wsLog, wsCtxD, nullptr);
        (void)hipFuncSetAttribute((const void*)k2_gemm2<2>,
                                  hipFuncAttributeMaxDynamicSharedMemorySize, smem2);
        k2_gemm2<2><<<dim3(NB * 4), dim3(512), smem2, stream>>>(
            Cg, wsLog, (const unsigned short*)wsCtxD, nullptr, Wout, Aout);
    } else if (ws_size >= WS_LOG_BYTES) {
        unsigned short* wsLog = (unsigned short*)d_ws;
        k1_gemm1_softmaxq<1><<<dim3(NB * 2), dim3(384), 0, stream>>>(Qg, Cg, wsLog, nullptr, nullptr);
        (void)hipFuncSetAttribute((const void*)k2_gemm2<1>,
                                  hipFuncAttributeMaxDynamicSharedMemorySize, smem2);
        k2_gemm2<1><<<dim3(NB * 4), dim3(512), smem2, stream>>>(
            Cg, wsLog, nullptr, nullptr, Wout, Aout);
    } else {
        k1_gemm1_softmaxq<0><<<dim3(NB * 2), dim3(384), 0, stream>>>(Qg, Cg, nullptr, nullptr, Aout);
        k15_softmaxs<<<dim3(NB, 24), dim3(256), 0, stream>>>(Aout);
        (void)hipFuncSetAttribute((const void*)k2_gemm2<0>,
                                  hipFuncAttributeMaxDynamicSharedMemorySize, smem2);
        k2_gemm2<0><<<dim3(NB * 4), dim3(512), smem2, stream>>>(
            Cg, nullptr, nullptr, Aout, Wout, Aout);
    }
}